// Round 1
// baseline (255.398 us; speedup 1.0000x reference)
//
#include <hip/hip_runtime.h>
#include <hip/hip_bf16.h>
#include <cstdint>

// LSTM cell with (diagonal) peephole connections, fused as:
//   K1: cast x|hx  -> bf16 A  [4096][2048]
//   K2: cast Wih|Whh -> bf16 W' [4096][2048], rows permuted so that an
//       N-tile of 128 = (32 h-values) x (4 gates):  n' = (h>>5)*128 + g*32 + (h&31)
//   K3: 128x128-tile bf16 MFMA GEMM (m97 structure: global_load_lds width=16,
//       ds_read_b128 frags, 16x16x32 MFMA) with the FULL LSTM epilogue fused:
//       each wave computes 32(M) x 128(N) so a single lane holds all 4 gates
//       of a given (m,h) in acc tiles j = g*2 + (h16) -> no cross-lane needed.

namespace {

constexpr int H  = 1024;   // hidden
constexpr int K2 = 2048;   // I + H
constexpr int BSZ = 4096;  // batch (M)
constexpr size_t OUT_CY = (size_t)BSZ * H;  // offset of cy in d_out

typedef __attribute__((ext_vector_type(8))) short bf16x8;
typedef __attribute__((ext_vector_type(4))) float f32x4;

__device__ __forceinline__ unsigned short f2bf(float f) {
  union { float f; uint32_t u; } v; v.f = f;
  uint32_t u = v.u;
  u += 0x7FFFu + ((u >> 16) & 1u);   // round-to-nearest-even
  return (unsigned short)(u >> 16);
}

__device__ __forceinline__ float sigm(float x) {
  return 1.0f / (1.0f + __expf(-x));
}
__device__ __forceinline__ float tanh_fast(float x) {
  // tanh(x) = 1 - 2/(exp(2x)+1); saturates correctly at +/-inf of expf
  return 1.0f - 2.0f / (1.0f + __expf(2.0f * x));
}

__device__ __forceinline__ void gload_lds16(const void* g, void* l) {
  __builtin_amdgcn_global_load_lds(
      (const __attribute__((address_space(1))) void*)g,
      (__attribute__((address_space(3))) void*)l, 16, 0, 0);
}

}  // namespace

// ---- K1: A = bf16([x | hx]),  [4096][2048] row-major -------------------------
__global__ __launch_bounds__(256) void cast_A_kernel(
    const float* __restrict__ x, const float* __restrict__ hx,
    unsigned short* __restrict__ A) {
  int t = blockIdx.x * 256 + threadIdx.x;
  int idx = t * 4;                    // flat bf16 index into A
  int m = idx >> 11;                  // /2048
  int k = idx & 2047;
  const float* src = (k < H) ? (x + (size_t)m * H + k)
                             : (hx + (size_t)m * H + (k - H));
  float4 v = *(const float4*)src;
  ushort4 o;
  o.x = f2bf(v.x); o.y = f2bf(v.y); o.z = f2bf(v.z); o.w = f2bf(v.w);
  *(ushort4*)(A + idx) = o;
}

// ---- K2: W' = bf16([Wih | Whh]) with gate-interleaved row permutation --------
__global__ __launch_bounds__(256) void cast_W_kernel(
    const float* __restrict__ wih, const float* __restrict__ whh,
    unsigned short* __restrict__ W) {
  int t = blockIdx.x * 256 + threadIdx.x;
  int idx = t * 4;
  int n = idx >> 11;                  // original gate-row: g*1024 + h
  int k = idx & 2047;
  int g = n >> 10;
  int h = n & 1023;
  int np = ((h >> 5) << 7) + (g << 5) + (h & 31);   // permuted row
  const float* src = (k < H) ? (wih + (size_t)n * H + k)
                             : (whh + (size_t)n * H + (k - H));
  float4 v = *(const float4*)src;
  ushort4 o;
  o.x = f2bf(v.x); o.y = f2bf(v.y); o.z = f2bf(v.z); o.w = f2bf(v.w);
  *(ushort4*)(W + (size_t)np * K2 + k) = o;
}

// ---- K3: fused GEMM + LSTM epilogue -----------------------------------------
// grid = (4096/128, 1024/32) = (32, 32), block = 256 (4 waves)
__global__ __launch_bounds__(256) void lstm_fused_gemm(
    const unsigned short* __restrict__ A,   // [4096][2048] bf16
    const unsigned short* __restrict__ W,   // [4096][2048] bf16, permuted rows
    const float* __restrict__ cx,
    const float* __restrict__ bias_ih, const float* __restrict__ bias_hh,
    const float* __restrict__ Wpi, const float* __restrict__ Wpf,
    float* __restrict__ out) {
  __shared__ __align__(16) unsigned short As[128 * 64];
  __shared__ __align__(16) unsigned short Ws[128 * 64];

  const int tid  = threadIdx.x;
  const int lane = tid & 63;
  const int wave = tid >> 6;
  const int m0 = blockIdx.x * 128;   // M-tile base
  const int h0 = blockIdx.y * 32;    // h base (32 h per block x 4 gates = 128 N)
  const int w0 = blockIdx.y * 128;   // W' row base

  // staging: thread loads 16B; lane-contiguous LDS layout (global_load_lds rule)
  const int srow = tid >> 3;         // 0..31
  const int scol = (tid & 7) * 8;    // bf16 col within K-tile

  f32x4 acc[2][8];
#pragma unroll
  for (int i = 0; i < 2; ++i)
#pragma unroll
    for (int j = 0; j < 8; ++j)
      acc[i][j] = (f32x4){0.f, 0.f, 0.f, 0.f};

  const int col = lane & 15;         // m (A-frag) / n (B-frag) / col (C/D)
  const int kq  = (lane >> 4) * 8;   // k offset within 32-wide k-step

  for (int kt = 0; kt < K2 / 64; ++kt) {
    const int kb = kt * 64;
    __syncthreads();                 // previous compute done before overwrite
#pragma unroll
    for (int q = 0; q < 4; ++q) {
      const int row = q * 32 + srow;
      const int ldsoff = q * 2048 + wave * 512;   // wave-uniform base (halves)
      gload_lds16(A + (size_t)(m0 + row) * K2 + kb + scol, &As[ldsoff]);
      gload_lds16(W + (size_t)(w0 + row) * K2 + kb + scol, &Ws[ldsoff]);
    }
    __syncthreads();                 // drains vmcnt(0) per barrier semantics

#pragma unroll
    for (int ks = 0; ks < 2; ++ks) {
      const int kk = ks * 32 + kq;
      bf16x8 a[2], b[8];
#pragma unroll
      for (int i = 0; i < 2; ++i)
        a[i] = *(const bf16x8*)&As[(wave * 32 + i * 16 + col) * 64 + kk];
#pragma unroll
      for (int j = 0; j < 8; ++j)
        b[j] = *(const bf16x8*)&Ws[(j * 16 + col) * 64 + kk];
#pragma unroll
      for (int i = 0; i < 2; ++i)
#pragma unroll
        for (int j = 0; j < 8; ++j)
          acc[i][j] = __builtin_amdgcn_mfma_f32_16x16x32_bf16(a[i], b[j], acc[i][j], 0, 0, 0);
    }
  }

  // ---- fused LSTM epilogue ----
  // C/D layout: col = lane&15, row = (lane>>4)*4 + r.
  // N-tile j covers gate g = j>>1, h-half hh = j&1  ->  gate g at acc[i][g*2+hh].
  const int quad = lane >> 4;
#pragma unroll
  for (int hh = 0; hh < 2; ++hh) {
    const int h = h0 + hh * 16 + col;
    const float bi = bias_ih[h]         + bias_hh[h];
    const float bf = bias_ih[H + h]     + bias_hh[H + h];
    const float bc = bias_ih[2 * H + h] + bias_hh[2 * H + h];
    const float bo = bias_ih[3 * H + h] + bias_hh[3 * H + h];
    const float di = Wpi[(size_t)h * (H + 1)];   // diagonal element
    const float df = Wpf[(size_t)h * (H + 1)];
#pragma unroll
    for (int i = 0; i < 2; ++i) {
#pragma unroll
      for (int r = 0; r < 4; ++r) {
        const int m = m0 + wave * 32 + i * 16 + quad * 4 + r;
        const float c  = cx[(size_t)m * H + h];
        const float ip = acc[i][0 + hh][r] + bi;
        const float fp = acc[i][2 + hh][r] + bf;
        const float cp = acc[i][4 + hh][r] + bc;
        const float op = acc[i][6 + hh][r] + bo;
        const float ig = sigm(ip + c * di);
        const float fg = sigm(fp + c * df);
        const float cg = tanh_fast(cp);
        const float cy = fg * c + ig * cg;
        const float og = sigm(op + cy * df);   // reference reuses W_peephole_f
        const float hy = og * tanh_fast(cy);
        out[(size_t)m * H + h] = hy;
        out[OUT_CY + (size_t)m * H + h] = cy;
      }
    }
  }
}

extern "C" void kernel_launch(void* const* d_in, const int* in_sizes, int n_in,
                              void* d_out, int out_size, void* d_ws, size_t ws_size,
                              hipStream_t stream) {
  const float* x   = (const float*)d_in[0];
  const float* hx  = (const float*)d_in[1];
  const float* cx  = (const float*)d_in[2];
  const float* wih = (const float*)d_in[3];
  const float* whh = (const float*)d_in[4];
  const float* bih = (const float*)d_in[5];
  const float* bhh = (const float*)d_in[6];
  const float* wpi = (const float*)d_in[7];
  const float* wpf = (const float*)d_in[8];
  // d_in[9] (W_peephole_o) is unused by the reference (it reuses W_peephole_f).
  float* out = (float*)d_out;

  unsigned short* Abf = (unsigned short*)d_ws;                 // 16.78 MB
  unsigned short* Wbf = Abf + (size_t)BSZ * K2;                // 16.78 MB

  // 4096*2048 bf16 elements, 4 per thread, 256 threads/block -> 8192 blocks
  cast_A_kernel<<<8192, 256, 0, stream>>>(x, hx, Abf);
  cast_W_kernel<<<8192, 256, 0, stream>>>(wih, whh, Wbf);

  dim3 grid(BSZ / 128, H / 32);
  lstm_fused_gemm<<<grid, 256, 0, stream>>>(Abf, Wbf, cx, bih, bhh, wpi, wpf, out);
}

// Round 2
// 228.232 us; speedup vs baseline: 1.1190x; 1.1190x over previous
//
#include <hip/hip_runtime.h>
#include <hip/hip_bf16.h>
#include <cstdint>

// LSTM cell with (diagonal) peephole connections.
//   K1: cast x|hx -> bf16 A [4096][2048]; cast Wih|Whh -> bf16 W' [4096][2048]
//       with gate-interleaved row permutation n' = (h>>4)*64 + g*16 + (h&15)
//       so every 64-wide N group holds all 4 gates for 16 h-values.
//   K2: 128x128-tile bf16 MFMA GEMM, 2x2 wave split (each wave 64Mx64N,
//       acc 4x4 of 16x16) -- cuts cross-wave LDS re-reads 20% vs 4x1.
//       XOR-swizzled LDS layout (chunk' = chunk ^ (row&7)) kills the 16-way
//       bank conflict of the 128B row stride while staying compatible with
//       global_load_lds' wave-uniform-base + lane*16 destination rule
//       (the swizzle is applied on the *global source* side during staging).
//       Full LSTM epilogue fused: lane-local, gate g lives in acc[i][g].

namespace {

constexpr int H   = 1024;   // hidden
constexpr int K2  = 2048;   // I + H
constexpr int BSZ = 4096;   // batch (M)
constexpr size_t OUT_CY = (size_t)BSZ * H;

typedef __attribute__((ext_vector_type(8))) short bf16x8;
typedef __attribute__((ext_vector_type(4))) float f32x4;

__device__ __forceinline__ unsigned short f2bf(float f) {
  union { float f; uint32_t u; } v; v.f = f;
  uint32_t u = v.u;
  u += 0x7FFFu + ((u >> 16) & 1u);   // round-to-nearest-even
  return (unsigned short)(u >> 16);
}

__device__ __forceinline__ float sigm(float x) {
  return 1.0f / (1.0f + __expf(-x));
}
__device__ __forceinline__ float tanh_fast(float x) {
  return 1.0f - 2.0f / (1.0f + __expf(2.0f * x));
}

__device__ __forceinline__ void gload_lds16(const void* g, void* l) {
  __builtin_amdgcn_global_load_lds(
      (const __attribute__((address_space(1))) void*)g,
      (__attribute__((address_space(3))) void*)l, 16, 0, 0);
}

}  // namespace

// ---- K1: both casts in one launch -------------------------------------------
// blocks [0, 8192): A = bf16([x|hx]); blocks [8192, 16384): W' permuted cast.
__global__ __launch_bounds__(256) void cast_kernel(
    const float* __restrict__ x, const float* __restrict__ hx,
    const float* __restrict__ wih, const float* __restrict__ whh,
    unsigned short* __restrict__ A, unsigned short* __restrict__ W) {
  int b = blockIdx.x;
  bool isW = b >= 8192;
  int t = (isW ? b - 8192 : b) * 256 + threadIdx.x;
  int idx = t * 4;
  int n = idx >> 11;
  int k = idx & 2047;
  const float* s0 = isW ? wih : x;
  const float* s1 = isW ? whh : hx;
  const float* src = (k < H) ? (s0 + (size_t)n * H + k)
                             : (s1 + (size_t)n * H + (k - H));
  float4 v = *(const float4*)src;
  ushort4 o;
  o.x = f2bf(v.x); o.y = f2bf(v.y); o.z = f2bf(v.z); o.w = f2bf(v.w);
  if (isW) {
    int g = n >> 10, h = n & 1023;
    int np = ((h >> 4) << 6) + (g << 4) + (h & 15);   // 64-wide gate groups
    *(ushort4*)(W + (size_t)np * K2 + k) = o;
  } else {
    *(ushort4*)(A + idx) = o;
  }
}

// ---- K2: fused GEMM + LSTM epilogue -----------------------------------------
// grid = (4096/128, 1024/32) = (32, 32), block = 256 (2x2 waves of 64Mx64N)
__global__ __launch_bounds__(256) void lstm_fused_gemm(
    const unsigned short* __restrict__ A,   // [4096][2048] bf16
    const unsigned short* __restrict__ W,   // [4096][2048] bf16, permuted rows
    const float* __restrict__ cx,
    const float* __restrict__ bias_ih, const float* __restrict__ bias_hh,
    const float* __restrict__ Wpi, const float* __restrict__ Wpf,
    float* __restrict__ out) {
  __shared__ __align__(16) unsigned short As[128 * 64];
  __shared__ __align__(16) unsigned short Ws[128 * 64];

  const int tid  = threadIdx.x;
  const int lane = tid & 63;
  const int wave = tid >> 6;
  const int wm = wave & 1;           // M half (64 rows)
  const int wn = wave >> 1;          // N half (64 rows)
  const int m0 = blockIdx.x * 128;
  const int h0 = blockIdx.y * 32;
  const int w0 = blockIdx.y * 128;   // W' row base

  // staging: thread loads 16B; LDS dest is lane-contiguous (rule), so the
  // XOR swizzle is applied to the global source chunk index.
  const int srow = tid >> 3;                       // 0..31
  const int scol = (((tid & 7) ^ (srow & 7)) << 3);  // swizzled chunk * 8 hw

  f32x4 acc[4][4];
#pragma unroll
  for (int i = 0; i < 4; ++i)
#pragma unroll
    for (int j = 0; j < 4; ++j)
      acc[i][j] = (f32x4){0.f, 0.f, 0.f, 0.f};

  const int col  = lane & 15;
  const int quad = lane >> 4;
  const int kq   = quad * 8;

  for (int kt = 0; kt < K2 / 64; ++kt) {
    const int kb = kt * 64;
    __syncthreads();
#pragma unroll
    for (int q = 0; q < 4; ++q) {
      const int row = q * 32 + srow;
      const int ldsoff = q * 2048 + wave * 512;    // wave-uniform base (hw)
      gload_lds16(A + (size_t)(m0 + row) * K2 + kb + scol, &As[ldsoff]);
      gload_lds16(W + (size_t)(w0 + row) * K2 + kb + scol, &Ws[ldsoff]);
    }
    __syncthreads();

#pragma unroll
    for (int ks = 0; ks < 2; ++ks) {
      const int kk = ks * 32 + kq;                 // halfword, multiple of 8
      bf16x8 a[4], b[4];
#pragma unroll
      for (int i = 0; i < 4; ++i) {
        const int R = wm * 64 + i * 16 + col;
        a[i] = *(const bf16x8*)&As[R * 64 + ((((kk >> 3) ^ (R & 7)) << 3))];
      }
#pragma unroll
      for (int j = 0; j < 4; ++j) {
        const int R = wn * 64 + j * 16 + col;
        b[j] = *(const bf16x8*)&Ws[R * 64 + ((((kk >> 3) ^ (R & 7)) << 3))];
      }
#pragma unroll
      for (int i = 0; i < 4; ++i)
#pragma unroll
        for (int j = 0; j < 4; ++j)
          acc[i][j] = __builtin_amdgcn_mfma_f32_16x16x32_bf16(a[i], b[j], acc[i][j], 0, 0, 0);
    }
  }

  // ---- fused LSTM epilogue ----
  // C/D layout: col = lane&15, row = quad*4 + r.  Wave wn's N range covers
  // h = h0 + wn*16 + col with gate g at acc[i][g].
  const int h = h0 + wn * 16 + col;
  const float bi = bias_ih[h]         + bias_hh[h];
  const float bf = bias_ih[H + h]     + bias_hh[H + h];
  const float bc = bias_ih[2 * H + h] + bias_hh[2 * H + h];
  const float bo = bias_ih[3 * H + h] + bias_hh[3 * H + h];
  const float di = Wpi[(size_t)h * (H + 1)];
  const float df = Wpf[(size_t)h * (H + 1)];
#pragma unroll
  for (int i = 0; i < 4; ++i) {
#pragma unroll
    for (int r = 0; r < 4; ++r) {
      const int m = m0 + wm * 64 + i * 16 + quad * 4 + r;
      const float c  = cx[(size_t)m * H + h];
      const float ip = acc[i][0][r] + bi;
      const float fp = acc[i][1][r] + bf;
      const float cp = acc[i][2][r] + bc;
      const float op = acc[i][3][r] + bo;
      const float ig = sigm(ip + c * di);
      const float fg = sigm(fp + c * df);
      const float cg = tanh_fast(cp);
      const float cy = fg * c + ig * cg;
      const float og = sigm(op + cy * df);   // reference reuses W_peephole_f
      const float hy = og * tanh_fast(cy);
      out[(size_t)m * H + h] = hy;
      out[OUT_CY + (size_t)m * H + h] = cy;
    }
  }
}

extern "C" void kernel_launch(void* const* d_in, const int* in_sizes, int n_in,
                              void* d_out, int out_size, void* d_ws, size_t ws_size,
                              hipStream_t stream) {
  const float* x   = (const float*)d_in[0];
  const float* hx  = (const float*)d_in[1];
  const float* cx  = (const float*)d_in[2];
  const float* wih = (const float*)d_in[3];
  const float* whh = (const float*)d_in[4];
  const float* bih = (const float*)d_in[5];
  const float* bhh = (const float*)d_in[6];
  const float* wpi = (const float*)d_in[7];
  const float* wpf = (const float*)d_in[8];
  // d_in[9] (W_peephole_o) unused: reference reuses W_peephole_f for outgate.
  float* out = (float*)d_out;

  unsigned short* Abf = (unsigned short*)d_ws;
  unsigned short* Wbf = Abf + (size_t)BSZ * K2;

  cast_kernel<<<16384, 256, 0, stream>>>(x, hx, wih, whh, Abf, Wbf);

  dim3 grid(BSZ / 128, H / 32);
  lstm_fused_gemm<<<grid, 256, 0, stream>>>(Abf, Wbf, cx, bih, bhh, wpi, wpf, out);
}

// Round 3
// 222.895 us; speedup vs baseline: 1.1458x; 1.0239x over previous
//
#include <hip/hip_runtime.h>
#include <hip/hip_bf16.h>
#include <cstdint>

// LSTM cell with (diagonal) peephole connections.
//   K1: cast x|hx -> bf16 A [4096][2048]; cast Wih|Whh -> bf16 W' [4096][2048]
//       with gate-interleaved row permutation n' = (h>>5)*128 + g*32 + (h&31)
//       so every 128-wide N group holds all 4 gates for 32 h-values.
//   K2: 128x128-tile bf16 MFMA GEMM, 128 threads = 2 waves, wave tile 64Mx128N
//       (acc 4x8) -- LDS-read bytes/flop drops 25% vs 64x64 wave tile
//       (24KB/1.05MF vs 16KB/0.52MF), balancing the LDS pipe (~30us/CU)
//       against the MFMA floor (~33us/CU).
//       16x16x32 MFMA kept (not 32x32x16): frag reads span 16 rows, so the
//       XOR swizzle (chunk' = chunk ^ (row&7)) keeps bank aliasing at 2-way
//       (free, m136); 32-row spans would force 4-way (1.58x).
//       Swizzle applied on the *global source* side during global_load_lds
//       staging (LDS dest must stay wave-uniform-base + lane*16).
//       Full LSTM epilogue fused, lane-local: gate g lives in acc[i][g*2+hh].

namespace {

constexpr int H   = 1024;   // hidden
constexpr int K2  = 2048;   // I + H
constexpr int BSZ = 4096;   // batch (M)
constexpr size_t OUT_CY = (size_t)BSZ * H;

typedef __attribute__((ext_vector_type(8))) short bf16x8;
typedef __attribute__((ext_vector_type(4))) float f32x4;

__device__ __forceinline__ unsigned short f2bf(float f) {
  union { float f; uint32_t u; } v; v.f = f;
  uint32_t u = v.u;
  u += 0x7FFFu + ((u >> 16) & 1u);   // round-to-nearest-even
  return (unsigned short)(u >> 16);
}

__device__ __forceinline__ float sigm(float x) {
  return 1.0f / (1.0f + __expf(-x));
}
__device__ __forceinline__ float tanh_fast(float x) {
  return 1.0f - 2.0f / (1.0f + __expf(2.0f * x));
}

__device__ __forceinline__ void gload_lds16(const void* g, void* l) {
  __builtin_amdgcn_global_load_lds(
      (const __attribute__((address_space(1))) void*)g,
      (__attribute__((address_space(3))) void*)l, 16, 0, 0);
}

}  // namespace

// ---- K1: both casts in one launch -------------------------------------------
// blocks [0, 8192): A = bf16([x|hx]); blocks [8192, 16384): W' permuted cast.
__global__ __launch_bounds__(256) void cast_kernel(
    const float* __restrict__ x, const float* __restrict__ hx,
    const float* __restrict__ wih, const float* __restrict__ whh,
    unsigned short* __restrict__ A, unsigned short* __restrict__ W) {
  int b = blockIdx.x;
  bool isW = b >= 8192;
  int t = (isW ? b - 8192 : b) * 256 + threadIdx.x;
  int idx = t * 4;
  int n = idx >> 11;
  int k = idx & 2047;
  const float* s0 = isW ? wih : x;
  const float* s1 = isW ? whh : hx;
  const float* src = (k < H) ? (s0 + (size_t)n * H + k)
                             : (s1 + (size_t)n * H + (k - H));
  float4 v = *(const float4*)src;
  ushort4 o;
  o.x = f2bf(v.x); o.y = f2bf(v.y); o.z = f2bf(v.z); o.w = f2bf(v.w);
  if (isW) {
    int g = n >> 10, h = n & 1023;
    int np = ((h >> 5) << 7) + (g << 5) + (h & 31);   // 128-wide gate groups
    *(ushort4*)(W + (size_t)np * K2 + k) = o;
  } else {
    *(ushort4*)(A + idx) = o;
  }
}

// ---- K2: fused GEMM + LSTM epilogue -----------------------------------------
// grid = (4096/128, 1024/32) = (32, 32), block = 128 (2 waves of 64Mx128N)
__global__ __launch_bounds__(128, 2) void lstm_fused_gemm(
    const unsigned short* __restrict__ A,   // [4096][2048] bf16
    const unsigned short* __restrict__ W,   // [4096][2048] bf16, permuted rows
    const float* __restrict__ cx,
    const float* __restrict__ bias_ih, const float* __restrict__ bias_hh,
    const float* __restrict__ Wpi, const float* __restrict__ Wpf,
    float* __restrict__ out) {
  __shared__ __align__(16) unsigned short As[128 * 64];
  __shared__ __align__(16) unsigned short Ws[128 * 64];

  const int tid  = threadIdx.x;
  const int lane = tid & 63;
  const int wave = tid >> 6;          // 0,1 = M half
  const int m0 = blockIdx.x * 128;
  const int h0 = blockIdx.y * 32;
  const int w0 = blockIdx.y * 128;    // W' row base

  // staging: thread loads 16B; LDS dest lane-contiguous (global_load_lds rule),
  // XOR swizzle applied to the global source chunk index.
  const int srow = tid >> 3;                         // 0..15
  const int scol = (((tid & 7) ^ (srow & 7)) << 3);  // swizzled chunk * 8 hw

  f32x4 acc[4][8];
#pragma unroll
  for (int i = 0; i < 4; ++i)
#pragma unroll
    for (int j = 0; j < 8; ++j)
      acc[i][j] = (f32x4){0.f, 0.f, 0.f, 0.f};

  const int col  = lane & 15;
  const int quad = lane >> 4;
  const int kq   = quad * 8;

  for (int kt = 0; kt < K2 / 64; ++kt) {
    const int kb = kt * 64;
    __syncthreads();
#pragma unroll
    for (int p = 0; p < 8; ++p) {
      const int row = p * 16 + srow;
      const int ldsoff = p * 1024 + wave * 512;      // hw units; wave-uniform
      gload_lds16(A + (size_t)(m0 + row) * K2 + kb + scol, &As[ldsoff]);
      gload_lds16(W + (size_t)(w0 + row) * K2 + kb + scol, &Ws[ldsoff]);
    }
    __syncthreads();

#pragma unroll
    for (int ks = 0; ks < 2; ++ks) {
      const int kk = ks * 32 + kq;                   // halfword, multiple of 8
      bf16x8 a[4], b[8];
#pragma unroll
      for (int i = 0; i < 4; ++i) {
        const int R = wave * 64 + i * 16 + col;
        a[i] = *(const bf16x8*)&As[R * 64 + (((kk >> 3) ^ (R & 7)) << 3)];
      }
#pragma unroll
      for (int j = 0; j < 8; ++j) {
        const int R = j * 16 + col;
        b[j] = *(const bf16x8*)&Ws[R * 64 + (((kk >> 3) ^ (R & 7)) << 3)];
      }
#pragma unroll
      for (int i = 0; i < 4; ++i)
#pragma unroll
        for (int j = 0; j < 8; ++j)
          acc[i][j] = __builtin_amdgcn_mfma_f32_16x16x32_bf16(a[i], b[j], acc[i][j], 0, 0, 0);
    }
  }

  // ---- fused LSTM epilogue ----
  // C/D layout: col = lane&15, row = quad*4 + r.
  // N-tile j: gate g = j>>1, h-half hh = j&1 -> gate g at acc[i][g*2+hh].
#pragma unroll
  for (int hh = 0; hh < 2; ++hh) {
    const int h = h0 + hh * 16 + col;
    const float bi = bias_ih[h]         + bias_hh[h];
    const float bf = bias_ih[H + h]     + bias_hh[H + h];
    const float bc = bias_ih[2 * H + h] + bias_hh[2 * H + h];
    const float bo = bias_ih[3 * H + h] + bias_hh[3 * H + h];
    const float di = Wpi[(size_t)h * (H + 1)];
    const float df = Wpf[(size_t)h * (H + 1)];
#pragma unroll
    for (int i = 0; i < 4; ++i) {
#pragma unroll
      for (int r = 0; r < 4; ++r) {
        const int m = m0 + wave * 64 + i * 16 + quad * 4 + r;
        const float c  = cx[(size_t)m * H + h];
        const float ip = acc[i][0 + hh][r] + bi;
        const float fp = acc[i][2 + hh][r] + bf;
        const float cp = acc[i][4 + hh][r] + bc;
        const float op = acc[i][6 + hh][r] + bo;
        const float ig = sigm(ip + c * di);
        const float fg = sigm(fp + c * df);
        const float cg = tanh_fast(cp);
        const float cy = fg * c + ig * cg;
        const float og = sigm(op + cy * df);   // reference reuses W_peephole_f
        const float hy = og * tanh_fast(cy);
        out[(size_t)m * H + h] = hy;
        out[OUT_CY + (size_t)m * H + h] = cy;
      }
    }
  }
}

extern "C" void kernel_launch(void* const* d_in, const int* in_sizes, int n_in,
                              void* d_out, int out_size, void* d_ws, size_t ws_size,
                              hipStream_t stream) {
  const float* x   = (const float*)d_in[0];
  const float* hx  = (const float*)d_in[1];
  const float* cx  = (const float*)d_in[2];
  const float* wih = (const float*)d_in[3];
  const float* whh = (const float*)d_in[4];
  const float* bih = (const float*)d_in[5];
  const float* bhh = (const float*)d_in[6];
  const float* wpi = (const float*)d_in[7];
  const float* wpf = (const float*)d_in[8];
  // d_in[9] (W_peephole_o) unused: reference reuses W_peephole_f for outgate.
  float* out = (float*)d_out;

  unsigned short* Abf = (unsigned short*)d_ws;
  unsigned short* Wbf = Abf + (size_t)BSZ * K2;

  cast_kernel<<<16384, 256, 0, stream>>>(x, hx, wih, whh, Abf, Wbf);

  dim3 grid(BSZ / 128, H / 32);
  lstm_fused_gemm<<<grid, 128, 0, stream>>>(Abf, Wbf, cx, bih, bhh, wpi, wpf, out);
}